// Round 1
// 381.990 us; speedup vs baseline: 1.0780x; 1.0780x over previous
//
#include <hip/hip_runtime.h>
#include <hip/hip_bf16.h>

#define DIM   1024
#define NVEC  128
#define BROWS 32768

typedef short s16x8 __attribute__((ext_vector_type(8)));
typedef float f32x4 __attribute__((ext_vector_type(4)));

__device__ __forceinline__ unsigned short f2bf(float f) {
    union { float f; unsigned int u; } c; c.f = f;
    unsigned int u = c.u;
    u += 0x7fffu + ((u >> 16) & 1u);   // round-to-nearest-even
    return (unsigned short)(u >> 16);
}

// ---------------------------------------------------------------------------
// K0: per-column normalize v; write VnT (fp32, [NVEC][DIM]) and VnT16 (bf16)
// ---------------------------------------------------------------------------
__global__ __launch_bounds__(256) void k_norm(const float* __restrict__ v,
                                              float* __restrict__ VnT,
                                              unsigned short* __restrict__ VnT16) {
    int i = blockIdx.x;          // which reflection vector
    int t = threadIdx.x;         // 256 threads
    __shared__ float red[4];
    float ss = 0.f;
    for (int d = t; d < DIM; d += 256) {
        float val = v[d * NVEC + i];
        ss += val * val;
    }
    for (int o = 32; o > 0; o >>= 1) ss += __shfl_down(ss, o, 64);
    if ((t & 63) == 0) red[t >> 6] = ss;
    __syncthreads();
    if (t == 0) red[0] = rsqrtf(red[0] + red[1] + red[2] + red[3]);
    __syncthreads();
    float rn = red[0];
    for (int d = t; d < DIM; d += 256) {
        float val = v[d * NVEC + i] * rn;
        VnT[i * DIM + d]   = val;
        VnT16[i * DIM + d] = f2bf(val);
    }
}

// ---------------------------------------------------------------------------
// K1: Gram matrix G[i][j] = <v_i, v_j>  (fp32, rows of VnT are coalesced)
// ---------------------------------------------------------------------------
__global__ __launch_bounds__(256) void k_gram(const float* __restrict__ VnT,
                                              float* __restrict__ G) {
    int i = blockIdx.x;
    int t = threadIdx.x, w = t >> 6, l = t & 63;
    float ri[16];
#pragma unroll
    for (int c = 0; c < 16; c++) ri[c] = VnT[i * DIM + c * 64 + l];
    for (int j = w; j < NVEC; j += 4) {
        const float* rj = VnT + j * DIM;
        float s = 0.f;
#pragma unroll
        for (int c = 0; c < 16; c++) s += ri[c] * rj[c * 64 + l];
        for (int o = 32; o > 0; o >>= 1) s += __shfl_down(s, o, 64);
        if (l == 0) G[i * NVEC + j] = s;
    }
}

// ---------------------------------------------------------------------------
// K2: T = R^{-1}, R = 0.5*I + strict_upper(G)   (tau=2 Householder larft)
// Parallel blocked triangular inversion. LDS = EXACTLY 64 KB (Ts only):
//  - diag 16x16 inverses: per-thread REGISTER back-substitution (unrolled)
//  - combine levels L=16,32,64 processed in 16-row panels top-down:
//      M16 = Ainv[panel,:] * B   then   B[panel,:] = -M16 * Cinv
//    M16 lives in the dead strict-lower triangle of Ts (rows 64..79, cols
//    0..63) — never touched by triangular reads/writes (all have col>=row
//    superblock base). Upper-tri Ainv => later panels read only
//    not-yet-overwritten B rows.
// ---------------------------------------------------------------------------
__global__ __launch_bounds__(256) void k_tinv(const float* __restrict__ G,
                                              float* __restrict__ Tout) {
    __shared__ __align__(16) float Ts[NVEC * NVEC];   // 65536 B exactly
    int t = threadIdx.x;

    // phase 0: R into LDS (0.5 on diag, zeros below)
    {
        int i = t >> 1, jb = (t & 1) * 64;
        for (int j = jb; j < jb + 64; j++) {
            float val = 0.f;
            if (j > i)       val = G[i * NVEC + j];
            else if (j == i) val = 0.5f;
            Ts[i * NVEC + j] = val;
        }
    }
    __syncthreads();

    // phase 1: invert 8 diagonal 16x16 blocks; thread t<128: blk=t>>4, col c=t&15
    {
        int blk = t >> 4, c = t & 15, rb = blk * 16;
        float xs[16];
        if (t < 128) {
#pragma unroll
            for (int jj = 0; jj < 16; jj++) xs[jj] = (jj == c) ? 2.f : 0.f;
#pragma unroll
            for (int i = 14; i >= 0; i--) {
                float s = 0.f;
#pragma unroll
                for (int j = i + 1; j < 16; j++)
                    s += Ts[(rb + i) * NVEC + rb + j] * xs[j];   // xs[j]=0 for j>c
                if (i < c) xs[i] = -2.f * s;
            }
        }
        __syncthreads();           // all reads of original diag blocks done
        if (t < 128) {
#pragma unroll
            for (int i = 0; i < 16; i++)
                if (i <= c) Ts[(rb + i) * NVEC + rb + c] = xs[i];  // keep sub-diag zeros
        }
        __syncthreads();
    }

    // phase 2: combine levels. 256 vec4-tasks per panel sub-phase (1/thread).
#pragma unroll
    for (int L = 16; L <= 64; L <<= 1) {
        int tpp = L << 2;                 // vec4 tasks per pair = 16*L/4
        int p   = t / tpp;                // pair id
        int rem = t % tpp;
        int r   = rem / (L >> 2);         // panel-local row 0..15
        int c0  = (rem % (L >> 2)) << 2;  // vec4 col base within block
        int a0  = p * (L << 1), b0 = a0 + L;
        int npanel = L >> 4;
        for (int pi = 0; pi < npanel; pi++) {
            int gr = a0 + pi * 16 + r;    // global A-side row
            // a: M[r][p*L + c0..+3] = sum_{k >= pi*16+r} Ainv[gr][a0+k] * B[a0+k][b0+c0..]
            f32x4 acc = {0.f, 0.f, 0.f, 0.f};
            for (int k = pi * 16 + r; k < L; k++)
                acc += Ts[gr * NVEC + a0 + k] *
                       *(const f32x4*)&Ts[(a0 + k) * NVEC + b0 + c0];
            *(f32x4*)&Ts[(64 + r) * NVEC + p * L + c0] = acc;
            __syncthreads();
            // b: B[gr][b0+c0..] = -sum_{k <= c0+3} M[r][p*L+k] * Cinv[b0+k][b0+c0..]
            //    (k>col terms vanish: sub-diag zeros inside diag 16-blocks)
            f32x4 acc2 = {0.f, 0.f, 0.f, 0.f};
            for (int k = 0; k <= c0 + 3; k++)
                acc2 += Ts[(64 + r) * NVEC + p * L + k] *
                        *(const f32x4*)&Ts[(b0 + k) * NVEC + b0 + c0];
            *(f32x4*)&Ts[gr * NVEC + b0 + c0] = -acc2;
            __syncthreads();
        }
    }

    // write out (explicit zeros below diag: lower triangle holds M scratch)
    for (int idx = t; idx < NVEC * NVEC; idx += 256) {
        int i = idx >> 7, j = idx & 127;
        Tout[idx] = (j >= i) ? Ts[idx] : 0.f;
    }
}

// ---------------------------------------------------------------------------
// K3: W[d][i] = sum_{j>=i} Vn[d][j] * T[i][j]   (W = V T^T), store bf16
// ---------------------------------------------------------------------------
__global__ __launch_bounds__(NVEC) void k_wmat(const float* __restrict__ VnT,
                                               const float* __restrict__ T,
                                               unsigned short* __restrict__ W16) {
    int d = blockIdx.x;
    int i = threadIdx.x;
    float s = 0.f;
    for (int j = i; j < NVEC; j++) s += VnT[j * DIM + d] * T[i * NVEC + j];
    W16[d * NVEC + i] = f2bf(s);
}

// ---------------------------------------------------------------------------
// K4 (fused): per 64-row block:
//   phase A: Y = x @ Vn   (K=1024, bf16 MFMA), Y kept on-chip (LDS, bf16)
//   phase B: out = x - Y @ W^T + b   (K=128), 8 column-tiles of 128
// x is read twice per block but the 2nd read (epilogue residual) hits L2.
// LDS aliased: phase A staging (As 9.2KB + Bs 18.4KB) reuses the same
// 52.2KB block as phase B (Ys 17.4KB + Ws 34.8KB).  2 blocks/CU.
// ---------------------------------------------------------------------------
#define LDA 72     // 64 + 8 pad (bf16 elems)
#define LDB 72
#define LDY 136    // 128 + 8 pad
#define LDW 136

__global__ __launch_bounds__(256) void k_fused(const float* __restrict__ x,
                                               const unsigned short* __restrict__ VnT16,
                                               const unsigned short* __restrict__ W16,
                                               const float* __restrict__ bias,
                                               float* __restrict__ out) {
    // phase B needs 64*LDY + 128*LDW = 8704 + 17408 = 26112 elems (52224 B)
    // phase A needs 64*LDA + 128*LDB = 4608 + 9216  = 13824 elems (aliased)
    __shared__ __align__(16) unsigned short smem[26112];
    unsigned short* As = smem;                 // [64][LDA]   (phase A)
    unsigned short* Bs = smem + 64 * LDA;      // [128][LDB]  (phase A)
    unsigned short* Ys = smem;                 // [64][LDY]   (phase B)
    unsigned short* Ws = smem + 64 * LDY;      // [128][LDW]  (phase B)

    int t = threadIdx.x;
    int r0 = blockIdx.x * 64;
    int w = t >> 6, l = t & 63, q = l >> 4, lm = l & 15;

    // ---------------- phase A: Y = x @ Vn ----------------
    f32x4 acc[8];
#pragma unroll
    for (int n = 0; n < 8; n++) acc[n] = (f32x4){0.f, 0.f, 0.f, 0.f};

    for (int k0 = 0; k0 < DIM; k0 += 64) {
        __syncthreads();
        {   // stage A: 64 rows x 64 k, fp32 -> bf16.  thread: row=t>>2, seg=t&3
            int row = t >> 2, seg = t & 3;
            const float4* src = (const float4*)(x + (size_t)(r0 + row) * DIM + k0);
#pragma unroll
            for (int jj = 0; jj < 4; jj++) {
                float4 f = src[seg + jj * 4];          // cols seg*4 + jj*16 (coalesced)
                ushort4 h;
                h.x = f2bf(f.x); h.y = f2bf(f.y); h.z = f2bf(f.z); h.w = f2bf(f.w);
                *(ushort4*)(As + row * LDA + seg * 4 + jj * 16) = h;
            }
        }
        {   // stage B: VnT16 rows n=0..127, cols k0..k0+63. thread: row=t>>1, half=t&1
            int row = t >> 1, half = t & 1;
            const uint4* src = (const uint4*)(VnT16 + (size_t)row * DIM + k0 + half * 32);
            uint4* dst = (uint4*)(Bs + row * LDB + half * 32);
#pragma unroll
            for (int jj = 0; jj < 4; jj++) dst[jj] = src[jj];
        }
        __syncthreads();

        int arow = w * 16 + lm;
#pragma unroll
        for (int kk = 0; kk < 64; kk += 32) {
            s16x8 a = *(const s16x8*)(As + arow * LDA + kk + q * 8);
#pragma unroll
            for (int nt = 0; nt < 8; nt++) {
                s16x8 b = *(const s16x8*)(Bs + (nt * 16 + lm) * LDB + kk + q * 8);
                acc[nt] = __builtin_amdgcn_mfma_f32_16x16x32_bf16(a, b, acc[nt], 0, 0, 0);
            }
        }
    }

    // Y (bf16) -> LDS.  C/D layout: col=lane&15, row=q*4+reg.
    __syncthreads();   // As/Bs reads done — Ys aliases them
    {
        int yrow = w * 16 + q * 4;
#pragma unroll
        for (int nt = 0; nt < 8; nt++)
#pragma unroll
            for (int r = 0; r < 4; r++)
                Ys[(yrow + r) * LDY + nt * 16 + lm] = f2bf(acc[nt][r]);
    }

    // ---------------- phase B: out = x - Y @ W^T + b ----------------
#pragma unroll 1
    for (int ct = 0; ct < 8; ct++) {
        int c0 = ct * 128;
        __syncthreads();   // ct=0: Ys written; ct>0: prev Ws reads done
        {   // stage W tile: rows d=c0..c0+127, all 128 cols. thread: row=t>>1, half=t&1
            int row = t >> 1, half = t & 1;
            const uint4* src = (const uint4*)(W16 + (size_t)(c0 + row) * NVEC + half * 64);
            uint4* dst = (uint4*)(Ws + row * LDW + half * 64);
#pragma unroll
            for (int jj = 0; jj < 8; jj++) dst[jj] = src[jj];
        }
        __syncthreads();

        f32x4 oacc[8];
#pragma unroll
        for (int n = 0; n < 8; n++) oacc[n] = (f32x4){0.f, 0.f, 0.f, 0.f};

        int arow = w * 16 + lm;
#pragma unroll
        for (int kk = 0; kk < NVEC; kk += 32) {
            s16x8 a = *(const s16x8*)(Ys + arow * LDY + kk + q * 8);
#pragma unroll
            for (int nt = 0; nt < 8; nt++) {
                s16x8 b = *(const s16x8*)(Ws + (nt * 16 + lm) * LDW + kk + q * 8);
                oacc[nt] = __builtin_amdgcn_mfma_f32_16x16x32_bf16(a, b, oacc[nt], 0, 0, 0);
            }
        }

        // epilogue: out = x - acc + b   (x re-read hits L2: same block, phase A)
        int orow = r0 + w * 16 + q * 4;
#pragma unroll
        for (int nt = 0; nt < 8; nt++) {
            int col = c0 + nt * 16 + lm;
            float bv = bias[col];
#pragma unroll
            for (int r = 0; r < 4; r++) {
                size_t idx = (size_t)(orow + r) * DIM + col;
                out[idx] = x[idx] - oacc[nt][r] + bv;
            }
        }
    }
}

// ---------------------------------------------------------------------------
extern "C" void kernel_launch(void* const* d_in, const int* in_sizes, int n_in,
                              void* d_out, int out_size, void* d_ws, size_t ws_size,
                              hipStream_t stream) {
    const float* x    = (const float*)d_in[0];
    const float* v    = (const float*)d_in[1];
    const float* bias = (const float*)d_in[2];
    float* out = (float*)d_out;

    char* ws = (char*)d_ws;
    float*          VnT   = (float*)(ws);                    // 512 KB  [NVEC][DIM] fp32
    unsigned short* VnT16 = (unsigned short*)(ws + 524288);  // 256 KB  [NVEC][DIM] bf16
    float*          G     = (float*)(ws + 786432);           // 64 KB   [NVEC][NVEC]
    float*          T     = (float*)(ws + 851968);           // 64 KB   [NVEC][NVEC]
    unsigned short* W16   = (unsigned short*)(ws + 917504);  // 256 KB  [DIM][NVEC] bf16

    k_norm<<<NVEC, 256, 0, stream>>>(v, VnT, VnT16);
    k_gram<<<NVEC, 256, 0, stream>>>(VnT, G);
    k_tinv<<<1, 256, 0, stream>>>(G, T);
    k_wmat<<<DIM, NVEC, 0, stream>>>(VnT, T, W16);
    k_fused<<<BROWS / 64, 256, 0, stream>>>(x, VnT16, W16, bias, out);
}